// Round 4
// baseline (476.493 us; speedup 1.0000x reference)
//
#include <hip/hip_runtime.h>
#include <hip/hip_bf16.h>

typedef short s16x8 __attribute__((ext_vector_type(8)));
typedef unsigned u32x4 __attribute__((ext_vector_type(4)));
typedef float f32x4 __attribute__((ext_vector_type(4)));
typedef float f32x2 __attribute__((ext_vector_type(2)));

// f32 -> bf16 bits, round-to-nearest-even (prep kernel only; not hot)
static __device__ __forceinline__ short f2bf(float f) {
    unsigned u = __builtin_bit_cast(unsigned, f);
    unsigned r = (u + 0x7fffu + ((u >> 16) & 1u)) >> 16;
    return (short)r;
}

// packed f32 pair -> 2x bf16 (RNE) in one dword (v_cvt_pk_bf16_f32)
static __device__ __forceinline__ unsigned pk2bf(float a, float b) {
    __hip_bfloat162 h = __float22bfloat162_rn(make_float2(a, b));
    unsigned r;
    __builtin_memcpy(&r, &h, sizeof(r));
    return r;
}

// Pack Wcat = [W1 | W3] (512 x 128) into bf16 B-fragment order with the
// PERMUTED k-order matching contiguous A-loads:
//   MFMA step kk (0..15): c = kk>>2, s = kk&3
//   B slot (lane l = g*16+mB, reg j) holds Wcat[k][n], where
//   k = c*128 + g*32 + s*8 + j   (bijective over (c,g,s,j))
//   n = nt*16 + mB
// bws[((kk*8+nt)*64 + l)*8 + j]
__global__ void prep_weights(const float* __restrict__ W1,
                             const float* __restrict__ W3,
                             short* __restrict__ bws) {
    int tid = blockIdx.x * blockDim.x + threadIdx.x;   // 0..65535
    int j  = tid & 7;
    int l  = (tid >> 3) & 63;
    int nt = (tid >> 9) & 7;
    int kk = tid >> 12;
    int g  = l >> 4;
    int k = ((kk >> 2) << 7) + (g << 5) + ((kk & 3) << 3) + j;
    int n = nt * 16 + (l & 15);
    float v = (n < 64) ? W1[k * 64 + n] : W3[k * 64 + (n - 64)];
    bws[tid] = f2bf(v);
}

__global__ __launch_bounds__(256, 2)
void mf2_main(const float* __restrict__ probs, const float* __restrict__ x,
              const short* __restrict__ bws,
              const float* __restrict__ b1, const float* __restrict__ W2,
              const float* __restrict__ b2, const float* __restrict__ b3,
              const float* __restrict__ W4, const float* __restrict__ b4,
              float* __restrict__ out)
{
    const int lane = threadIdx.x & 63;
    const int wv   = threadIdx.x >> 6;
    const int g    = lane >> 4;     // 0..3  (k-group: owns k = c*128 + g*32 + [0,32))
    const int m    = lane & 15;     // 0..15 (A-row within tile / C-col)
    const long rowBase = (long)blockIdx.x * 128 + wv * 32;   // 32 rows per wave

    f32x4 acc[2][8];
    #pragma unroll
    for (int t = 0; t < 2; ++t)
        #pragma unroll
        for (int nt = 0; nt < 8; ++nt)
            acc[t][nt] = (f32x4){0.f, 0.f, 0.f, 0.f};

    // A loads: lane reads 128 CONTIGUOUS bytes of row (rowBase + t*16 + m)
    // per outer step c: x[row][c*128 + g*32 .. +32)  (512 B contiguous per row-visit)
    const float* xp = x + (rowBase + m) * 512 + g * 32;
    const s16x8* bp = (const s16x8*)bws + lane;

    // preload c=0 raw A: ra[t][q] holds k = c*128 + g*32 + q*4 + [0,4)
    f32x4 ra[2][8];
    #pragma unroll
    for (int t = 0; t < 2; ++t)
        #pragma unroll
        for (int q = 0; q < 8; ++q)
            ra[t][q] = __builtin_nontemporal_load((const f32x4*)(xp + t * (16 * 512)) + q);

    #pragma unroll
    for (int c = 0; c < 4; ++c) {
        // convert raw A -> 4 sub-step fragments per tile (k = ...+ s*8 + [0,8))
        s16x8 a[2][4];
        #pragma unroll
        for (int t = 0; t < 2; ++t)
            #pragma unroll
            for (int s = 0; s < 4; ++s) {
                u32x4 pa;
                pa[0] = pk2bf(ra[t][2 * s][0],     ra[t][2 * s][1]);
                pa[1] = pk2bf(ra[t][2 * s][2],     ra[t][2 * s][3]);
                pa[2] = pk2bf(ra[t][2 * s + 1][0], ra[t][2 * s + 1][1]);
                pa[3] = pk2bf(ra[t][2 * s + 1][2], ra[t][2 * s + 1][3]);
                a[t][s] = __builtin_bit_cast(s16x8, pa);
            }

        // prefetch next c (hides HBM latency under the 64-MFMA block)
        if (c < 3) {
            #pragma unroll
            for (int t = 0; t < 2; ++t)
                #pragma unroll
                for (int q = 0; q < 8; ++q)
                    ra[t][q] = __builtin_nontemporal_load(
                        (const f32x4*)(xp + t * (16 * 512) + (c + 1) * 128) + q);
        }

        // 4 MFMA sub-steps; B fragments streamed from L2
        #pragma unroll
        for (int s = 0; s < 4; ++s) {
            const int kk = c * 4 + s;
            s16x8 b[8];
            #pragma unroll
            for (int nt = 0; nt < 8; ++nt) b[nt] = bp[kk * 512 + nt * 64];
            #pragma unroll
            for (int nt = 0; nt < 8; ++nt)
                #pragma unroll
                for (int t = 0; t < 2; ++t)
                    acc[t][nt] = __builtin_amdgcn_mfma_f32_16x16x32_bf16(a[t][s], b[nt], acc[t][nt], 0, 0, 0);
        }
    }

    // ---- epilogue (weight/bias loads deferred past the loop) ----
    float w2r[4][4];
    float w4r[4][2];
    float biasr[8];
    #pragma unroll
    for (int nt = 0; nt < 4; ++nt) {
        const int col = m + 16 * nt;
        f32x4 w2v = *(const f32x4*)(W2 + col * 4);
        #pragma unroll
        for (int c = 0; c < 4; ++c) w2r[nt][c] = w2v[c];
        f32x2 w4v = *(const f32x2*)(W4 + col * 2);
        w4r[nt][0] = w4v[0]; w4r[nt][1] = w4v[1];
    }
    #pragma unroll
    for (int nt = 0; nt < 8; ++nt) {
        const int col = m + 16 * nt;
        biasr[nt] = (col < 64) ? b1[col] : b3[col - 64];
    }
    float b2v[4], b4v[2];
    #pragma unroll
    for (int c = 0; c < 4; ++c) b2v[c] = b2[c];
    #pragma unroll
    for (int c = 0; c < 2; ++c) b4v[c] = b4[c];

    // bias+relu, layer-2 partials, 16-lane butterfly reduce.
    // C layout: lane holds row 4*g + r (within tile t), col m + 16*nt.
    float own[6] = {0.f, 0.f, 0.f, 0.f, 0.f, 0.f};
    #pragma unroll
    for (int t = 0; t < 2; ++t) {
        #pragma unroll
        for (int r = 0; r < 4; ++r) {
            float v[6] = {0.f, 0.f, 0.f, 0.f, 0.f, 0.f};
            #pragma unroll
            for (int nt = 0; nt < 4; ++nt) {
                float h = fmaxf(acc[t][nt][r] + biasr[nt], 0.f);
                v[0] += h * w2r[nt][0];
                v[1] += h * w2r[nt][1];
                v[2] += h * w2r[nt][2];
                v[3] += h * w2r[nt][3];
            }
            #pragma unroll
            for (int j = 0; j < 4; ++j) {
                float h = fmaxf(acc[t][4 + j][r] + biasr[4 + j], 0.f);
                v[4] += h * w4r[j][0];
                v[5] += h * w4r[j][1];
            }
            #pragma unroll
            for (int msk = 1; msk <= 8; msk <<= 1) {
                #pragma unroll
                for (int c = 0; c < 6; ++c) v[c] += __shfl_xor(v[c], msk, 64);
            }
            if (m == t * 4 + r) {
                #pragma unroll
                for (int c = 0; c < 6; ++c) own[c] = v[c];
            }
        }
    }

    // one lane per row finishes: sigmoid head + 2-class softmax
    if (m < 8) {
        const int t = m >> 2, r = m & 3;
        const long row = rowBase + t * 16 + g * 4 + r;
        f32x4 pr = *(const f32x4*)(probs + row * 4);   // p00 p01 p10 p11
        float mu1[2], mu2[2], icv[2];
        #pragma unroll
        for (int c = 0; c < 2; ++c) {
            mu1[c] = 1.0f / (1.0f + __expf(-(own[c]     + b2v[c])));
            mu2[c] = 1.0f / (1.0f + __expf(-(own[2 + c] + b2v[2 + c])));
            icv[c] = 1.0f / (1.0f + __expf(-(own[4 + c] + b4v[c])));
        }
        float res[2];
        #pragma unroll
        for (int c = 0; c < 2; ++c) {
            float p0 = pr[c], p1 = pr[2 + c];
            float m12 = fminf(fmaxf(mu1[c], mu2[c]) + icv[c], 1.0f);
            res[c] = (p0 <= p1) ? (p0 * mu1[c] + (p1 - p0) * m12)
                                : (p1 * mu2[c] + (p0 - p1) * m12);
        }
        float d01 = res[0] - res[1];
        f32x2 o;
        o[0] = 1.0f / (1.0f + __expf(-d01));
        o[1] = 1.0f / (1.0f + __expf(d01));
        *(f32x2*)(out + row * 2) = o;
    }
}

extern "C" void kernel_launch(void* const* d_in, const int* in_sizes, int n_in,
                              void* d_out, int out_size, void* d_ws, size_t ws_size,
                              hipStream_t stream)
{
    const float* probs = (const float*)d_in[0];
    const float* x     = (const float*)d_in[1];
    const float* W1    = (const float*)d_in[2];
    const float* b1    = (const float*)d_in[3];
    const float* W2    = (const float*)d_in[4];
    const float* b2    = (const float*)d_in[5];
    const float* W3    = (const float*)d_in[6];
    const float* b3    = (const float*)d_in[7];
    const float* W4    = (const float*)d_in[8];
    const float* b4    = (const float*)d_in[9];
    float* out = (float*)d_out;
    short* bws = (short*)d_ws;   // 512*128 bf16 = 128 KiB

    hipLaunchKernelGGL(prep_weights, dim3(256), dim3(256), 0, stream, W1, W3, bws);
    hipLaunchKernelGGL(mf2_main, dim3(2048), dim3(256), 0, stream,
                       probs, x, bws, b1, W2, b2, b3, W4, b4, out);
}

// Round 5
// 125.902 us; speedup vs baseline: 3.7846x; 3.7846x over previous
//
#include <hip/hip_runtime.h>
#include <hip/hip_bf16.h>

typedef short s16x8 __attribute__((ext_vector_type(8)));
typedef unsigned u32x4 __attribute__((ext_vector_type(4)));
typedef float f32x4 __attribute__((ext_vector_type(4)));
typedef float f32x2 __attribute__((ext_vector_type(2)));

// f32 -> bf16 bits, round-to-nearest-even (prep kernel only; not hot)
static __device__ __forceinline__ short f2bf(float f) {
    unsigned u = __builtin_bit_cast(unsigned, f);
    unsigned r = (u + 0x7fffu + ((u >> 16) & 1u)) >> 16;
    return (short)r;
}

// packed f32 pair -> 2x bf16 (RNE) in one dword (v_cvt_pk_bf16_f32)
static __device__ __forceinline__ unsigned pk2bf(float a, float b) {
    __hip_bfloat162 h = __float22bfloat162_rn(make_float2(a, b));
    unsigned r;
    __builtin_memcpy(&r, &h, sizeof(r));
    return r;
}

// Pack Wcat = [W1 | W3] (512 x 128) into bf16 B-fragment order (R1 mapping):
// bws[((kk*8+nt)*64 + l)*8 + j] = Wcat[kk*32 + 8*(l>>4) + j][nt*16 + (l&15)]
__global__ void prep_weights(const float* __restrict__ W1,
                             const float* __restrict__ W3,
                             short* __restrict__ bws) {
    int tid = blockIdx.x * blockDim.x + threadIdx.x;   // 0..65535
    int j  = tid & 7;
    int l  = (tid >> 3) & 63;
    int nt = (tid >> 9) & 7;
    int kk = tid >> 12;
    int k = kk * 32 + ((l >> 4) << 3) + j;
    int n = nt * 16 + (l & 15);
    float v = (n < 64) ? W1[k * 64 + n] : W3[k * 64 + (n - 64)];
    bws[tid] = f2bf(v);
}

__global__ __launch_bounds__(1024, 4)
void mf2_main(const float* __restrict__ probs, const float* __restrict__ x,
              const short* __restrict__ bws,
              const float* __restrict__ b1, const float* __restrict__ W2,
              const float* __restrict__ b2, const float* __restrict__ b3,
              const float* __restrict__ W4, const float* __restrict__ b4,
              float* __restrict__ out)
{
    __shared__ short bsh[512 * 128];   // 128 KiB: full packed [W1|W3] tile

    const int tid  = threadIdx.x;      // 0..1023 (16 waves)
    const int lane = tid & 63;
    const int wv   = tid >> 6;         // 0..15
    const int g    = lane >> 4;        // 0..3  (k-chunk group)
    const int m    = lane & 15;        // 0..15 (A-row within tile / C-col)
    const long rowBase = (long)blockIdx.x * 512 + wv * 32;   // 32 rows per wave

    // ---- stage packed B into LDS once per block (coalesced, conflict-free) ----
    {
        const f32x4* src = (const f32x4*)bws;   // 8192 x 16B
        f32x4* dst = (f32x4*)bsh;
        #pragma unroll
        for (int it = 0; it < 8; ++it) {
            const int idx = it * 1024 + tid;
            dst[idx] = src[idx];
        }
    }
    __syncthreads();

    f32x4 acc[2][8];
    #pragma unroll
    for (int t = 0; t < 2; ++t)
        #pragma unroll
        for (int nt = 0; nt < 8; ++nt)
            acc[t][nt] = (f32x4){0.f, 0.f, 0.f, 0.f};

    // A loads: lane reads 8 contiguous f32 of row (rowBase + t*16 + m), k-chunk 8*g
    const float* xp = x + (rowBase + m) * 512 + g * 8;
    const s16x8* bls = (const s16x8*)bsh + lane;

    #pragma unroll 2
    for (int kk = 0; kk < 16; ++kk) {
        s16x8 a[2];
        #pragma unroll
        for (int t = 0; t < 2; ++t) {
            const float* p = xp + t * (16 * 512) + kk * 32;
            f32x4 lo = *(const f32x4*)p;
            f32x4 hi = *(const f32x4*)(p + 4);
            u32x4 pa;
            pa[0] = pk2bf(lo[0], lo[1]);
            pa[1] = pk2bf(lo[2], lo[3]);
            pa[2] = pk2bf(hi[0], hi[1]);
            pa[3] = pk2bf(hi[2], hi[3]);
            a[t] = __builtin_bit_cast(s16x8, pa);
        }
        #pragma unroll
        for (int nt = 0; nt < 8; ++nt) {
            s16x8 b = bls[kk * 512 + nt * 64];
            acc[0][nt] = __builtin_amdgcn_mfma_f32_16x16x32_bf16(a[0], b, acc[0][nt], 0, 0, 0);
            acc[1][nt] = __builtin_amdgcn_mfma_f32_16x16x32_bf16(a[1], b, acc[1][nt], 0, 0, 0);
        }
    }

    // ---- epilogue (weight/bias loads deferred past the loop) ----
    float w2r[4][4];
    float w4r[4][2];
    float biasr[8];
    #pragma unroll
    for (int nt = 0; nt < 4; ++nt) {
        const int col = m + 16 * nt;
        f32x4 w2v = *(const f32x4*)(W2 + col * 4);
        #pragma unroll
        for (int c = 0; c < 4; ++c) w2r[nt][c] = w2v[c];
        f32x2 w4v = *(const f32x2*)(W4 + col * 2);
        w4r[nt][0] = w4v[0]; w4r[nt][1] = w4v[1];
    }
    #pragma unroll
    for (int nt = 0; nt < 8; ++nt) {
        const int col = m + 16 * nt;
        biasr[nt] = (col < 64) ? b1[col] : b3[col - 64];
    }
    float b2v[4], b4v[2];
    #pragma unroll
    for (int c = 0; c < 4; ++c) b2v[c] = b2[c];
    #pragma unroll
    for (int c = 0; c < 2; ++c) b4v[c] = b4[c];

    // bias+relu, layer-2 partials, 16-lane butterfly reduce.
    // C layout: lane holds row 4*g + r (within tile t), col m + 16*nt.
    float own[6] = {0.f, 0.f, 0.f, 0.f, 0.f, 0.f};
    #pragma unroll
    for (int t = 0; t < 2; ++t) {
        #pragma unroll
        for (int r = 0; r < 4; ++r) {
            float v[6] = {0.f, 0.f, 0.f, 0.f, 0.f, 0.f};
            #pragma unroll
            for (int nt = 0; nt < 4; ++nt) {
                float h = fmaxf(acc[t][nt][r] + biasr[nt], 0.f);
                v[0] += h * w2r[nt][0];
                v[1] += h * w2r[nt][1];
                v[2] += h * w2r[nt][2];
                v[3] += h * w2r[nt][3];
            }
            #pragma unroll
            for (int j = 0; j < 4; ++j) {
                float h = fmaxf(acc[t][4 + j][r] + biasr[4 + j], 0.f);
                v[4] += h * w4r[j][0];
                v[5] += h * w4r[j][1];
            }
            #pragma unroll
            for (int msk = 1; msk <= 8; msk <<= 1) {
                #pragma unroll
                for (int c = 0; c < 6; ++c) v[c] += __shfl_xor(v[c], msk, 64);
            }
            if (m == t * 4 + r) {
                #pragma unroll
                for (int c = 0; c < 6; ++c) own[c] = v[c];
            }
        }
    }

    // one lane per row finishes: sigmoid head + 2-class softmax
    if (m < 8) {
        const int t = m >> 2, r = m & 3;
        const long row = rowBase + t * 16 + g * 4 + r;
        f32x4 pr = *(const f32x4*)(probs + row * 4);   // p00 p01 p10 p11
        float mu1[2], mu2[2], icv[2];
        #pragma unroll
        for (int c = 0; c < 2; ++c) {
            mu1[c] = 1.0f / (1.0f + __expf(-(own[c]     + b2v[c])));
            mu2[c] = 1.0f / (1.0f + __expf(-(own[2 + c] + b2v[2 + c])));
            icv[c] = 1.0f / (1.0f + __expf(-(own[4 + c] + b4v[c])));
        }
        float res[2];
        #pragma unroll
        for (int c = 0; c < 2; ++c) {
            float p0 = pr[c], p1 = pr[2 + c];
            float m12 = fminf(fmaxf(mu1[c], mu2[c]) + icv[c], 1.0f);
            res[c] = (p0 <= p1) ? (p0 * mu1[c] + (p1 - p0) * m12)
                                : (p1 * mu2[c] + (p0 - p1) * m12);
        }
        float d01 = res[0] - res[1];
        f32x2 o;
        o[0] = 1.0f / (1.0f + __expf(-d01));
        o[1] = 1.0f / (1.0f + __expf(d01));
        *(f32x2*)(out + row * 2) = o;
    }
}

extern "C" void kernel_launch(void* const* d_in, const int* in_sizes, int n_in,
                              void* d_out, int out_size, void* d_ws, size_t ws_size,
                              hipStream_t stream)
{
    const float* probs = (const float*)d_in[0];
    const float* x     = (const float*)d_in[1];
    const float* W1    = (const float*)d_in[2];
    const float* b1    = (const float*)d_in[3];
    const float* W2    = (const float*)d_in[4];
    const float* b2    = (const float*)d_in[5];
    const float* W3    = (const float*)d_in[6];
    const float* b3    = (const float*)d_in[7];
    const float* W4    = (const float*)d_in[8];
    const float* b4    = (const float*)d_in[9];
    float* out = (float*)d_out;
    short* bws = (short*)d_ws;   // 512*128 bf16 = 128 KiB

    hipLaunchKernelGGL(prep_weights, dim3(256), dim3(256), 0, stream, W1, W3, bws);
    hipLaunchKernelGGL(mf2_main, dim3(512), dim3(1024), 0, stream,
                       probs, x, bws, b1, W2, b2, b3, W4, b4, out);
}